// Round 1
// baseline (1967.936 us; speedup 1.0000x reference)
//
#include <hip/hip_runtime.h>

#define B_ 16
#define N_ 2048
#define IN_ 12
#define H_ 64
#define K_ 16

// ---------------------------------------------------------------------------
// Kernel 1: emb = relu(x@W1+b1)@W2+b2  (one 64-lane wave per row),
// also writes s = 1/max(||emb_row||, 1e-12) to ws.
// ---------------------------------------------------------------------------
__global__ __launch_bounds__(256) void emb_kernel(
    const float* __restrict__ x, const float* __restrict__ W1,
    const float* __restrict__ b1, const float* __restrict__ W2,
    const float* __restrict__ b2, float* __restrict__ emb_out,
    float* __restrict__ sref) {
  const int lane = threadIdx.x & 63;
  const int wid = threadIdx.x >> 6;
  const long long row = (long long)blockIdx.x * 4 + wid;  // 0..32767

  const float* xr = x + row * IN_;
  float xv[IN_];
#pragma unroll
  for (int k = 0; k < IN_; ++k) xv[k] = xr[k];  // broadcast loads (same addr per wave)

  float acc = b1[lane];
#pragma unroll
  for (int k = 0; k < IN_; ++k) acc += xv[k] * W1[k * H_ + lane];
  float h = fmaxf(acc, 0.f);

  float e = b2[lane];
#pragma unroll
  for (int j = 0; j < H_; ++j) {
    float hj = __shfl(h, j, 64);
    e += hj * W2[j * H_ + lane];
  }

  float ss = e * e;
#pragma unroll
  for (int off = 32; off; off >>= 1) ss += __shfl_xor(ss, off, 64);
  float s = 1.0f / fmaxf(sqrtf(ss), 1e-12f);

  emb_out[row * H_ + lane] = e;
  if (lane == 0) sref[row] = s;
}

// ---------------------------------------------------------------------------
// Kernel 2: per block: 2 rows of sim (f32, exact), top-16 extraction,
// write adj rows (zeros + scatter). 256 threads.
// ---------------------------------------------------------------------------
__global__ __launch_bounds__(256) void sim_topk_kernel(
    const float* __restrict__ emb, const float* __restrict__ sref,
    float* __restrict__ adj) {
  __shared__ float4 NI4[2][H_ / 4];     // scaled row-i embeddings
  __shared__ float SIM[2][N_];          // 16 KB
  __shared__ float red_v[4];
  __shared__ int red_i[4];
  __shared__ float wv[2][K_];
  __shared__ int wi[2][K_];

  const int t = threadIdx.x;
  const int pair = blockIdx.x;          // 0..16383
  const int b = pair >> 10;             // 1024 row-pairs per batch
  const int i0 = (pair & 1023) * 2;
  const long long rowbase = (long long)b * N_;
  const float* embB = emb + rowbase * H_;

  // ---- load the two i-rows, pre-scaled by 1/||.|| ----
  if (t < 2 * H_) {
    const int r = t >> 6, d = t & 63;
    const long long row = rowbase + i0 + r;
    ((float*)NI4[r])[d] = emb[row * H_ + d] * sref[row];
  }
  __syncthreads();

  // ---- compute sim for both rows: 8 columns per thread ----
  for (int k = 0; k < 8; ++k) {
    const int j = t + (k << 8);
    const float4* ej = (const float4*)(embB + (long long)j * H_);
    const float sj = sref[rowbase + j];
    float4 a0 = make_float4(0.f, 0.f, 0.f, 0.f);
    float4 a1 = make_float4(0.f, 0.f, 0.f, 0.f);
#pragma unroll
    for (int dg = 0; dg < H_ / 4; ++dg) {
      const float4 v = ej[dg];
      const float4 n0 = NI4[0][dg];   // broadcast LDS reads
      const float4 n1 = NI4[1][dg];
      a0.x += n0.x * v.x; a0.y += n0.y * v.y; a0.z += n0.z * v.z; a0.w += n0.w * v.w;
      a1.x += n1.x * v.x; a1.y += n1.y * v.y; a1.z += n1.z * v.z; a1.w += n1.w * v.w;
    }
    SIM[0][j] = (a0.x + a0.y + a0.z + a0.w) * sj;
    SIM[1][j] = (a1.x + a1.y + a1.z + a1.w) * sj;
  }
  __syncthreads();

  // ---- top-16 per row: threads [0,128) -> row 0, [128,256) -> row 1 ----
  const int rg = t >> 7;
  const int sub = t & 127;

  // local max over interleaved segment (ascending j => lowest-index tie-break)
  float lv = -3.f; int li = 0;
#pragma unroll
  for (int m = 0; m < 16; ++m) {
    const int j = sub + (m << 7);
    const float v = SIM[rg][j];
    if (v > lv) { lv = v; li = j; }
  }

  for (int it = 0; it < K_; ++it) {
    // wave-level argmax (ties -> lower index)
    float v = lv; int idx = li;
#pragma unroll
    for (int off = 32; off; off >>= 1) {
      const float ov = __shfl_xor(v, off, 64);
      const int oi = __shfl_xor(idx, off, 64);
      if (ov > v || (ov == v && oi < idx)) { v = ov; idx = oi; }
    }
    const int w = t >> 6;
    if ((t & 63) == 0) { red_v[w] = v; red_i[w] = idx; }
    __syncthreads();
    // combine the row-group's two wave partials
    const float v0 = red_v[rg * 2], v1 = red_v[rg * 2 + 1];
    const int j0 = red_i[rg * 2], j1 = red_i[rg * 2 + 1];
    float bv; int bi;
    if (v1 > v0 || (v1 == v0 && j1 < j0)) { bv = v1; bi = j1; }
    else { bv = v0; bi = j0; }
    if (sub == 0) { wv[rg][it] = bv; wi[rg][it] = bi; }
    // owner thread removes the winner and rescans its segment
    if ((bi & 127) == sub) {
      SIM[rg][bi] = -3.f;
      lv = -3.f; li = 0;
#pragma unroll
      for (int m = 0; m < 16; ++m) {
        const int j = sub + (m << 7);
        const float vv = SIM[rg][j];
        if (vv > lv) { lv = vv; li = j; }
      }
    }
    __syncthreads();
  }

  // ---- write adj: zero both rows, then scatter the 16 winners ----
  const long long abase = ((long long)b * N_ + i0) * N_;
  float4* arow0 = (float4*)(adj + abase);
  float4* arow1 = (float4*)(adj + abase + N_);
  const float4 z = make_float4(0.f, 0.f, 0.f, 0.f);
#pragma unroll
  for (int k = 0; k < 2; ++k) {
    arow0[t + (k << 8)] = z;
    arow1[t + (k << 8)] = z;
  }
  __syncthreads();  // compiler drains vmcnt(0) before s_barrier -> zeros land first
  if (t < 2 * K_) {
    const int r = t >> 4, q = t & 15;
    adj[abase + (long long)r * N_ + wi[r][q]] = wv[r][q];
  }
}

extern "C" void kernel_launch(void* const* d_in, const int* in_sizes, int n_in,
                              void* d_out, int out_size, void* d_ws, size_t ws_size,
                              hipStream_t stream) {
  const float* x  = (const float*)d_in[0];
  const float* W1 = (const float*)d_in[1];
  const float* b1 = (const float*)d_in[2];
  const float* W2 = (const float*)d_in[3];
  const float* b2 = (const float*)d_in[4];

  float* adj = (float*)d_out;                                   // B*N*N
  float* embo = (float*)d_out + (long long)B_ * N_ * N_;        // B*N*H
  float* sref = (float*)d_ws;                                   // B*N floats

  // Kernel 1: embeddings + inverse norms (4 rows per 256-thread block)
  emb_kernel<<<(B_ * N_) / 4, 256, 0, stream>>>(x, W1, b1, W2, b2, embo, sref);

  // Kernel 2: sim + top-k + adj write (2 rows per block)
  sim_topk_kernel<<<(B_ * N_) / 2, 256, 0, stream>>>(embo, sref, adj);
}

// Round 4
// 348.277 us; speedup vs baseline: 5.6505x; 5.6505x over previous
//
#include <hip/hip_runtime.h>

#define B_ 16
#define N_ 2048
#define IN_ 12
#define H_ 64
#define K_ 16

// Skewed LDS index: row-major [r][k] tiles, stride 68 + 4-float skew per 4 rows.
// A-frag reads (16-lane broadcast groups, r0 step 8): quads {0,2,4,...} distinct -> conflict-free.
// B-frag reads (4-lane broadcast groups, c step 4): 20*tx mod 32 -> 2-way max (free).
// 16B alignment: 4*(68r + 4(r>>2) + k), k%4==0 -> multiple of 16.
#define IDX(r, k) ((r) * 68 + ((r) >> 2) * 4 + (k))

// ---------------------------------------------------------------------------
// Kernel A: emb = relu(x@W1+b1)@W2+b2 (one wave per row); sref = 1/max(||e||,eps)
// (bit-identical to round 1)
// ---------------------------------------------------------------------------
__global__ __launch_bounds__(256) void emb_kernel(
    const float* __restrict__ x, const float* __restrict__ W1,
    const float* __restrict__ b1, const float* __restrict__ W2,
    const float* __restrict__ b2, float* __restrict__ emb_out,
    float* __restrict__ sref) {
  const int lane = threadIdx.x & 63;
  const int wid = threadIdx.x >> 6;
  const long long row = (long long)blockIdx.x * 4 + wid;  // 0..32767

  const float* xr = x + row * IN_;
  float xv[IN_];
#pragma unroll
  for (int k = 0; k < IN_; ++k) xv[k] = xr[k];

  float acc = b1[lane];
#pragma unroll
  for (int k = 0; k < IN_; ++k) acc += xv[k] * W1[k * H_ + lane];
  float h = fmaxf(acc, 0.f);

  float e = b2[lane];
#pragma unroll
  for (int j = 0; j < H_; ++j) {
    float hj = __shfl(h, j, 64);
    e += hj * W2[j * H_ + lane];
  }

  float ss = e * e;
#pragma unroll
  for (int off = 32; off; off >>= 1) ss += __shfl_xor(ss, off, 64);
  float s = 1.0f / fmaxf(sqrtf(ss), 1e-12f);

  emb_out[row * H_ + lane] = e;
  if (lane == 0) sref[row] = s;
}

// ---------------------------------------------------------------------------
// Kernel B: sim tile GEMM, 128x64 per block, 8x4 outputs/thread.
// Per-value arithmetic mirrors round 1 exactly:
//   A side: fl(e_i * s_i) rounded at LDS store (R1's NI4)
//   accumulate: float4 of 4 FMA chains over dg = 0..15 ascending
//   epilogue: (a.x + a.y + a.z + a.w) * s_j
// ---------------------------------------------------------------------------
__global__ __launch_bounds__(256) void sim_kernel(
    const float* __restrict__ emb, const float* __restrict__ sref,
    float* __restrict__ adj) {
  __shared__ float As[8824];  // IDX(127,63)+1
  __shared__ float Bs[4408];  // IDX(63,63)+1

  const int t = threadIdx.x;
  const int nTj = N_ / 64;                 // 32
  const int tilesPerB = (N_ / 128) * nTj;  // 512
  const int b = blockIdx.x / tilesPerB;
  const int tl = blockIdx.x % tilesPerB;
  const int ti = tl / nTj, tj = tl % nTj;

  const float* Eb = emb + (size_t)b * N_ * H_;
  const float* srb = sref + b * N_;

  // ---- stage A-tile: rows ti*128..+128, pre-scaled by s_i ----
  {
    const int r = t >> 1;              // 0..127
    const int k0 = (t & 1) * 32;       // 0 or 32
    const float sA = srb[ti * 128 + r];
    const float* src = Eb + (size_t)(ti * 128 + r) * H_ + k0;
#pragma unroll
    for (int i = 0; i < 8; ++i) {
      const float4 v = *(const float4*)(src + i * 4);
      float4 w;
      w.x = v.x * sA; w.y = v.y * sA; w.z = v.z * sA; w.w = v.w * sA;
      *(float4*)&As[IDX(r, k0 + i * 4)] = w;
    }
  }
  // ---- stage B-tile: rows tj*64..+64, raw e_j ----
  {
    const int r = t >> 2;              // 0..63
    const int k0 = (t & 3) * 16;
    const float* src = Eb + (size_t)(tj * 64 + r) * H_ + k0;
#pragma unroll
    for (int i = 0; i < 4; ++i) {
      const float4 v = *(const float4*)(src + i * 4);
      *(float4*)&Bs[IDX(r, k0 + i * 4)] = v;
    }
  }
  __syncthreads();

  const int tx = t & 15, ty = t >> 4;
  const int r0 = ty * 8, c0 = tx * 4;

  float4 acc[8][4];
#pragma unroll
  for (int rr = 0; rr < 8; ++rr)
#pragma unroll
    for (int cc = 0; cc < 4; ++cc) acc[rr][cc] = make_float4(0.f, 0.f, 0.f, 0.f);

  int aoff[8], boff[4];
#pragma unroll
  for (int rr = 0; rr < 8; ++rr) aoff[rr] = IDX(r0 + rr, 0);
#pragma unroll
  for (int cc = 0; cc < 4; ++cc) boff[cc] = IDX(c0 + cc, 0);

#pragma unroll 4
  for (int dg = 0; dg < 16; ++dg) {
    float4 av[8], bv[4];
#pragma unroll
    for (int rr = 0; rr < 8; ++rr) av[rr] = *(const float4*)&As[aoff[rr] + dg * 4];
#pragma unroll
    for (int cc = 0; cc < 4; ++cc) bv[cc] = *(const float4*)&Bs[boff[cc] + dg * 4];
#pragma unroll
    for (int rr = 0; rr < 8; ++rr)
#pragma unroll
      for (int cc = 0; cc < 4; ++cc) {
        acc[rr][cc].x += av[rr].x * bv[cc].x;
        acc[rr][cc].y += av[rr].y * bv[cc].y;
        acc[rr][cc].z += av[rr].z * bv[cc].z;
        acc[rr][cc].w += av[rr].w * bv[cc].w;
      }
  }

  // ---- epilogue: (x+y+z+w) * s_j, store ----
  const float4 sjv = *(const float4*)(srb + tj * 64 + c0);
  float* out = adj + (size_t)b * N_ * N_ + (size_t)(ti * 128 + r0) * N_ + tj * 64 + c0;
#pragma unroll
  for (int rr = 0; rr < 8; ++rr) {
    float4 o;
    o.x = (acc[rr][0].x + acc[rr][0].y + acc[rr][0].z + acc[rr][0].w) * sjv.x;
    o.y = (acc[rr][1].x + acc[rr][1].y + acc[rr][1].z + acc[rr][1].w) * sjv.y;
    o.z = (acc[rr][2].x + acc[rr][2].y + acc[rr][2].z + acc[rr][2].w) * sjv.z;
    o.w = (acc[rr][3].x + acc[rr][3].y + acc[rr][3].z + acc[rr][3].w) * sjv.w;
    *(float4*)(out + (size_t)rr * N_) = o;
  }
}

// ---------------------------------------------------------------------------
// Kernel C: in-place top-16 per row. One wave per row, row in registers.
// u64 key = mono(value)<<32 | (N-1-j): total order, value desc / index asc
// (== lax.top_k tie-break). 16 butterfly rounds, lazy owner rescan,
// single merged keep-masked write.
// ---------------------------------------------------------------------------
__device__ __forceinline__ unsigned mono32(float v) {
  unsigned u = __float_as_uint(v);
  return u ^ ((unsigned)((int)u >> 31) | 0x80000000u);
}

__global__ __launch_bounds__(256) void topk_kernel(float* __restrict__ adj) {
  const int lane = threadIdx.x & 63;
  const int wid = threadIdx.x >> 6;
  const size_t row = (size_t)blockIdx.x * 4 + wid;  // 0..32767
  float* rp = adj + row * N_;

  // element j = m*256 + lane*4 + c lives in vals[m*4+c]
  float vals[32];
#pragma unroll
  for (int m = 0; m < 8; ++m) {
    const float4 v = *((const float4*)rp + m * 64 + lane);
    vals[m * 4 + 0] = v.x; vals[m * 4 + 1] = v.y;
    vals[m * 4 + 2] = v.z; vals[m * 4 + 3] = v.w;
  }

  unsigned long long lk = 0ull;
#pragma unroll
  for (int m = 0; m < 8; ++m)
#pragma unroll
    for (int c = 0; c < 4; ++c) {
      const int j = m * 256 + lane * 4 + c;
      const unsigned long long key =
          ((unsigned long long)mono32(vals[m * 4 + c]) << 32) |
          (unsigned)(N_ - 1 - j);
      if (key > lk) lk = key;
    }

  unsigned taken = 0u;
  for (int it = 0; it < K_; ++it) {
    unsigned long long bk = lk;
#pragma unroll
    for (int off = 32; off; off >>= 1) {
      const unsigned long long ok = __shfl_xor(bk, off, 64);
      if (ok > bk) bk = ok;
    }
    const int j = N_ - 1 - (int)(bk & 0xFFFFFFFFull);
    if (((j >> 2) & 63) == lane) {           // owner lane pops + rescans
      const int slot = ((j >> 8) << 2) | (j & 3);
      taken |= 1u << slot;
      lk = 0ull;
#pragma unroll
      for (int m = 0; m < 8; ++m)
#pragma unroll
        for (int c = 0; c < 4; ++c) {
          const int s2 = m * 4 + c;
          if (!((taken >> s2) & 1u)) {
            const int jj = m * 256 + lane * 4 + c;
            const unsigned long long key =
                ((unsigned long long)mono32(vals[s2]) << 32) |
                (unsigned)(N_ - 1 - jj);
            if (key > lk) lk = key;
          }
        }
    }
  }

  // merged write: winners keep value, everything else zero
#pragma unroll
  for (int m = 0; m < 8; ++m) {
    float4 o;
    o.x = ((taken >> (m * 4 + 0)) & 1u) ? vals[m * 4 + 0] : 0.f;
    o.y = ((taken >> (m * 4 + 1)) & 1u) ? vals[m * 4 + 1] : 0.f;
    o.z = ((taken >> (m * 4 + 2)) & 1u) ? vals[m * 4 + 2] : 0.f;
    o.w = ((taken >> (m * 4 + 3)) & 1u) ? vals[m * 4 + 3] : 0.f;
    *((float4*)rp + m * 64 + lane) = o;
  }
}

extern "C" void kernel_launch(void* const* d_in, const int* in_sizes, int n_in,
                              void* d_out, int out_size, void* d_ws, size_t ws_size,
                              hipStream_t stream) {
  const float* x  = (const float*)d_in[0];
  const float* W1 = (const float*)d_in[1];
  const float* b1 = (const float*)d_in[2];
  const float* W2 = (const float*)d_in[3];
  const float* b2 = (const float*)d_in[4];

  float* adj  = (float*)d_out;                              // B*N*N
  float* embo = (float*)d_out + (size_t)B_ * N_ * N_;       // B*N*H
  float* sref = (float*)d_ws;                               // B*N floats

  emb_kernel<<<(B_ * N_) / 4, 256, 0, stream>>>(x, W1, b1, W2, b2, embo, sref);
  sim_kernel<<<B_ * (N_ / 128) * (N_ / 64), 256, 0, stream>>>(embo, sref, adj);
  topk_kernel<<<(B_ * N_) / 4, 256, 0, stream>>>(adj);
}